// Round 1
// baseline (161.776 us; speedup 1.0000x reference)
//
#include <hip/hip_runtime.h>
#include <math.h>

#define BB 4
#define NN 2048
#define MM 128
#define DD 64
#define NEG_SLOPE 0.2f

// ---------------------------------------------------------------------------
// k0: u_r[k] = sum_d attn_r[d] * W_dst[d*D+k];  c_e = sum_d W_edge[d]*attn_e[d]
// ---------------------------------------------------------------------------
__global__ void prep_kernel(const float* __restrict__ W_dst,
                            const float* __restrict__ W_edge,
                            const float* __restrict__ attn_r,
                            const float* __restrict__ attn_e,
                            float* __restrict__ u_r,
                            float* __restrict__ c_e) {
    int k = threadIdx.x;  // 0..63
    float acc = 0.f;
    for (int d = 0; d < DD; ++d) acc += attn_r[d] * W_dst[d * DD + k];
    u_r[k] = acc;
    if (k == 0) {
        float c = 0.f;
        for (int d = 0; d < DD; ++d) c += W_edge[d] * attn_e[d];
        *c_e = c;
    }
}

// ---------------------------------------------------------------------------
// k1: hs[row,d] = sum_k feat_src[row,k] * W_src[d,k];  el[row] = hs[row,:]·attn_l
// One wave (64 lanes) per row; 4 rows per block.
// ---------------------------------------------------------------------------
__global__ __launch_bounds__(256) void proj_src_kernel(
        const float* __restrict__ fs,
        const float* __restrict__ W_src,
        const float* __restrict__ attn_l,
        float* __restrict__ hs,
        float* __restrict__ el) {
    int w = threadIdx.x >> 6;     // wave id 0..3
    int lane = threadIdx.x & 63;  // = output d
    int row = blockIdx.x * 4 + w; // < B*N
    __shared__ float rows[4][DD];
    rows[w][lane] = fs[row * DD + lane];
    __syncthreads();
    float acc = 0.f;
    const float* wrow = W_src + lane * DD;
#pragma unroll
    for (int k = 0; k < DD; ++k) acc += rows[w][k] * wrow[k];
    hs[row * DD + lane] = acc;
    // el = sum_d hs_d * attn_l[d] (wave reduce over 64 lanes)
    float v = acc * attn_l[lane];
    for (int off = 32; off > 0; off >>= 1) v += __shfl_down(v, off, 64);
    if (lane == 0) el[row] = v;
}

// ---------------------------------------------------------------------------
// k2: er[i] = feat_dst[i,:] · u_r   (i over B*M = 512)
// ---------------------------------------------------------------------------
__global__ void er_kernel(const float* __restrict__ fd,
                          const float* __restrict__ u_r,
                          float* __restrict__ er) {
    int i = blockIdx.x * blockDim.x + threadIdx.x;
    if (i >= BB * MM) return;
    float acc = 0.f;
    for (int k = 0; k < DD; ++k) acc += fd[i * DD + k] * u_r[k];
    er[i] = acc;
}

// ---------------------------------------------------------------------------
// k3: per (b,m): masked-leaky scores over n, softmax over n, then
//     out[b,m,d] = sigmoid( (W_edge[d]*sum_n fe*p + sum_n hs[n,d]*p[n]) / denom )
// 256 threads / block, 512 blocks.
// ---------------------------------------------------------------------------
__global__ __launch_bounds__(256) void attn_agg_kernel(
        const float* __restrict__ fe, const int* __restrict__ adj,
        const float* __restrict__ hs, const float* __restrict__ el,
        const float* __restrict__ er, const float* __restrict__ W_edge,
        const float* __restrict__ c_e_p, float* __restrict__ out) {
    int bm = blockIdx.x;
    int b = bm >> 7;   // / M
    int m = bm & 127;  // % M
    int t = threadIdx.x;
    int w = t >> 6, lane = t & 63;

    __shared__ float sp[NN];          // scores -> probs (8 KB)
    __shared__ float red_max[4];
    __shared__ float red_sum[4];
    __shared__ float red_sfe[4];
    __shared__ float partial[4][DD];

    float c_e = *c_e_p;
    float er_bm = er[bm];
    const float* fe_b = fe + (size_t)b * NN * MM + m;
    const int* adj_b = adj + (size_t)b * NN * MM + m;
    const float* el_b = el + b * NN;

    // Phase A: scores + local max
    float fe_loc[8];
    float lmax = -INFINITY;
#pragma unroll
    for (int i = 0; i < 8; ++i) {
        int n = t + i * 256;
        float f = fe_b[(size_t)n * MM];
        fe_loc[i] = f;
        float a = el_b[n] + c_e * f + er_bm;
        a = a > 0.f ? a : NEG_SLOPE * a;
        a = (adj_b[(size_t)n * MM] == 1) ? a : -INFINITY;
        sp[n] = a;
        lmax = fmaxf(lmax, a);
    }
    for (int off = 32; off > 0; off >>= 1)
        lmax = fmaxf(lmax, __shfl_xor(lmax, off, 64));
    if (lane == 0) red_max[w] = lmax;
    __syncthreads();
    float vmax = fmaxf(fmaxf(red_max[0], red_max[1]),
                       fmaxf(red_max[2], red_max[3]));

    // Phase B: exp, local sum and fe-weighted sum (each thread owns its n's)
    float lsum = 0.f, lsfe = 0.f;
#pragma unroll
    for (int i = 0; i < 8; ++i) {
        int n = t + i * 256;
        float a = sp[n];
        float e = (a == -INFINITY) ? 0.f : expf(a - vmax);
        sp[n] = e;
        lsum += e;
        lsfe += fe_loc[i] * e;
    }
    for (int off = 32; off > 0; off >>= 1) {
        lsum += __shfl_xor(lsum, off, 64);
        lsfe += __shfl_xor(lsfe, off, 64);
    }
    if (lane == 0) { red_sum[w] = lsum; red_sfe[w] = lsfe; }
    __syncthreads();
    float denom = red_sum[0] + red_sum[1] + red_sum[2] + red_sum[3];
    float sfe = red_sfe[0] + red_sfe[1] + red_sfe[2] + red_sfe[3];

    // Phase C: aggregated[d] = sum_n hs[n,d] * p[n]   (4 n-groups x 64 d)
    int d = t & 63, g = t >> 6;
    float acc = 0.f;
    const float* hs_b = hs + (size_t)b * NN * DD;
    for (int n = g; n < NN; n += 4)
        acc += hs_b[n * DD + d] * sp[n];
    partial[g][d] = acc;
    __syncthreads();
    if (t < DD) {
        float s = partial[0][t] + partial[1][t] + partial[2][t] + partial[3][t];
        float agg = (W_edge[t] * sfe + s) / denom;
        out[(size_t)bm * DD + t] = 1.f / (1.f + expf(-agg));
    }
}

extern "C" void kernel_launch(void* const* d_in, const int* in_sizes, int n_in,
                              void* d_out, int out_size, void* d_ws, size_t ws_size,
                              hipStream_t stream) {
    const float* feat_src  = (const float*)d_in[0];
    const float* feat_dst  = (const float*)d_in[1];
    const float* feat_edge = (const float*)d_in[2];
    const int*   adj       = (const int*)d_in[3];
    const float* W_src     = (const float*)d_in[4];
    const float* W_dst     = (const float*)d_in[5];
    const float* W_edge    = (const float*)d_in[6];
    const float* attn_l    = (const float*)d_in[7];
    const float* attn_r    = (const float*)d_in[8];
    const float* attn_e    = (const float*)d_in[9];
    float* out = (float*)d_out;

    float* ws  = (float*)d_ws;
    float* hs  = ws;                    // B*N*D = 524288
    float* el  = hs + BB * NN * DD;     // B*N   = 8192
    float* er  = el + BB * NN;          // B*M   = 512
    float* u_r = er + BB * MM;          // D     = 64
    float* c_e = u_r + DD;              // 1

    prep_kernel<<<1, 64, 0, stream>>>(W_dst, W_edge, attn_r, attn_e, u_r, c_e);
    proj_src_kernel<<<(BB * NN) / 4, 256, 0, stream>>>(feat_src, W_src, attn_l, hs, el);
    er_kernel<<<2, 256, 0, stream>>>(feat_dst, u_r, er);
    attn_agg_kernel<<<BB * MM, 256, 0, stream>>>(feat_edge, adj, hs, el, er,
                                                 W_edge, c_e, out);
}

// Round 2
// 39.079 us; speedup vs baseline: 4.1397x; 4.1397x over previous
//
#include <hip/hip_runtime.h>
#include <math.h>

#define BB 4
#define NN 2048
#define MM 128
#define DD 64
#define NEG_SLOPE 0.2f

// ---------------------------------------------------------------------------
// proj: hs[row,d] = feat_src[row,:] . W_src[d,:];  el[row] = hs[row,:] . attn_l
// 16 rows/block, W row kept in registers per lane, rows broadcast from LDS.
// ---------------------------------------------------------------------------
__global__ __launch_bounds__(256) void proj_kernel(
        const float* __restrict__ fs, const float* __restrict__ W_src,
        const float* __restrict__ attn_l, float* __restrict__ hs,
        float* __restrict__ el) {
    int t = threadIdx.x, lane = t & 63, w = t >> 6;
    int row0 = blockIdx.x * 16;
    __shared__ float4 rows4[16][16];               // 16 rows x 64 floats
    const float4* fs4 = (const float4*)(fs + (size_t)row0 * DD);
    ((float4*)rows4)[t] = fs4[t];
    float4 wreg[16];
    const float4* w4 = (const float4*)(W_src + (size_t)lane * DD);
#pragma unroll
    for (int k = 0; k < 16; ++k) wreg[k] = w4[k];
    float al = attn_l[lane];
    __syncthreads();
    float acc[4] = {0.f, 0.f, 0.f, 0.f};
#pragma unroll
    for (int k = 0; k < 16; ++k) {
#pragma unroll
        for (int j = 0; j < 4; ++j) {
            float4 rv = rows4[w * 4 + j][k];
            acc[j] += rv.x * wreg[k].x + rv.y * wreg[k].y +
                      rv.z * wreg[k].z + rv.w * wreg[k].w;
        }
    }
#pragma unroll
    for (int j = 0; j < 4; ++j) {
        int row = row0 + w * 4 + j;
        hs[(size_t)row * DD + lane] = acc[j];
        float v = acc[j] * al;
        for (int off = 32; off > 0; off >>= 1) v += __shfl_xor(v, off, 64);
        if (lane == 0) el[row] = v;
    }
}

// ---------------------------------------------------------------------------
// er: u_r[k] = sum_d attn_r[d]*W_dst[d,k] (in LDS);  er[i] = fd[i,:] . u_r
// ---------------------------------------------------------------------------
__global__ __launch_bounds__(256) void er_kernel(
        const float* __restrict__ fd, const float* __restrict__ W_dst,
        const float* __restrict__ attn_r, float* __restrict__ er) {
    __shared__ float u_r[DD];
    int t = threadIdx.x;
    if (t < DD) {
        float a = 0.f;
        for (int d = 0; d < DD; ++d) a += attn_r[d] * W_dst[d * DD + t];
        u_r[t] = a;
    }
    __syncthreads();
    int i = blockIdx.x * 256 + t;                  // 2 blocks -> 512
    float acc = 0.f;
    const float4* fd4 = (const float4*)(fd + (size_t)i * DD);
    const float4* ur4 = (const float4*)u_r;
#pragma unroll
    for (int k = 0; k < 16; ++k) {
        float4 f = fd4[k], u = ur4[k];
        acc += f.x * u.x + f.y * u.y + f.z * u.z + f.w * u.w;
    }
    er[i] = acc;
}

// ---------------------------------------------------------------------------
// ts: scores (masked leaky) computed with coalesced fe/adj reads, then
// LDS-transposed and written as st_s[b][m][n], st_f[b][m][n] (contig in n).
// grid (64 n-tiles of 32, B), 256 threads.
// ---------------------------------------------------------------------------
__global__ __launch_bounds__(256) void ts_kernel(
        const float* __restrict__ fe, const int* __restrict__ adj,
        const float* __restrict__ el, const float* __restrict__ er,
        const float* __restrict__ W_edge, const float* __restrict__ attn_e,
        float* __restrict__ st_s, float* __restrict__ st_f) {
    int b = blockIdx.y;
    int n0 = blockIdx.x * 32;
    int t = threadIdx.x;
    __shared__ float s_lds[32][129];
    __shared__ float f_lds[32][129];
    float c_e = 0.f;
    for (int d = 0; d < DD; ++d) c_e += W_edge[d] * attn_e[d];
    int m = t & 127, nh = t >> 7;                  // 2 rows per iter
    float er_m = er[b * MM + m];
    const float* fe_p = fe + ((size_t)b * NN + n0) * MM + m;
    const int* adj_p = adj + ((size_t)b * NN + n0) * MM + m;
    const float* el_p = el + b * NN + n0;
#pragma unroll
    for (int it = 0; it < 16; ++it) {
        int n = nh + it * 2;
        float f = fe_p[(size_t)n * MM];
        int a = adj_p[(size_t)n * MM];
        float s = el_p[n] + c_e * f + er_m;
        s = s > 0.f ? s : NEG_SLOPE * s;
        s = (a == 1) ? s : -INFINITY;
        s_lds[n][m] = s;
        f_lds[n][m] = f;
    }
    __syncthreads();
#pragma unroll
    for (int j = 0; j < 16; ++j) {
        int e = t + j * 256;
        int mm = e >> 5, n = e & 31;
        size_t o = ((size_t)(b * MM + mm)) * NN + n0 + n;
        st_s[o] = s_lds[n][mm];
        st_f[o] = f_lds[n][mm];
    }
}

// ---------------------------------------------------------------------------
// soft: per (b,m) row: max, p=exp(s-max), denom, sfe; writes p-hat = p/denom
// and ssfe = sfe/denom. Rows are contiguous (8KB). 512 blocks.
// ---------------------------------------------------------------------------
__global__ __launch_bounds__(256) void soft_kernel(
        const float* __restrict__ st_s, const float* __restrict__ st_f,
        float* __restrict__ pt, float* __restrict__ ssfe) {
    int bm = blockIdx.x, t = threadIdx.x;
    int lane = t & 63, w = t >> 6;
    const float4* s4 = (const float4*)(st_s + (size_t)bm * NN);
    const float4* f4 = (const float4*)(st_f + (size_t)bm * NN);
    float4 sv[2], fv[2];
    sv[0] = s4[t * 2]; sv[1] = s4[t * 2 + 1];
    fv[0] = f4[t * 2]; fv[1] = f4[t * 2 + 1];
    float lmax = -INFINITY;
#pragma unroll
    for (int i = 0; i < 2; ++i)
        lmax = fmaxf(lmax, fmaxf(fmaxf(sv[i].x, sv[i].y), fmaxf(sv[i].z, sv[i].w)));
    for (int off = 32; off > 0; off >>= 1)
        lmax = fmaxf(lmax, __shfl_xor(lmax, off, 64));
    __shared__ float rmax[4], rsum[4], rsfe[4];
    if (lane == 0) rmax[w] = lmax;
    __syncthreads();
    float vmax = fmaxf(fmaxf(rmax[0], rmax[1]), fmaxf(rmax[2], rmax[3]));
    float4 pv[2];
    float lsum = 0.f, lsfe = 0.f;
#pragma unroll
    for (int i = 0; i < 2; ++i) {
        pv[i].x = expf(sv[i].x - vmax);
        pv[i].y = expf(sv[i].y - vmax);
        pv[i].z = expf(sv[i].z - vmax);
        pv[i].w = expf(sv[i].w - vmax);
        lsum += pv[i].x + pv[i].y + pv[i].z + pv[i].w;
        lsfe += fv[i].x * pv[i].x + fv[i].y * pv[i].y +
                fv[i].z * pv[i].z + fv[i].w * pv[i].w;
    }
    for (int off = 32; off > 0; off >>= 1) {
        lsum += __shfl_xor(lsum, off, 64);
        lsfe += __shfl_xor(lsfe, off, 64);
    }
    if (lane == 0) { rsum[w] = lsum; rsfe[w] = lsfe; }
    __syncthreads();
    float denom = rsum[0] + rsum[1] + rsum[2] + rsum[3];
    float sfe = rsfe[0] + rsfe[1] + rsfe[2] + rsfe[3];
    float inv = 1.f / denom;
    if (t == 0) ssfe[bm] = sfe * inv;
    float4* pt4 = (float4*)(pt + (size_t)bm * NN);
#pragma unroll
    for (int i = 0; i < 2; ++i) {
        float4 o;
        o.x = pv[i].x * inv; o.y = pv[i].y * inv;
        o.z = pv[i].z * inv; o.w = pv[i].w * inv;
        pt4[t * 2 + i] = o;
    }
}

// ---------------------------------------------------------------------------
// agg1: partial[b][nc][m][d] = sum_{n in chunk} phat[b,m,n]*hs[b,n,d]
// grid (nc=16, mt=8, b=4) = 512 blocks; LDS-staged hs chunk + p tile.
// ---------------------------------------------------------------------------
__global__ __launch_bounds__(256) void agg1_kernel(
        const float* __restrict__ pt, const float* __restrict__ hs,
        float* __restrict__ pbuf) {
    int nc = blockIdx.x, mt = blockIdx.y, b = blockIdx.z;
    int t = threadIdx.x;
    __shared__ float hs_lds[128][64];              // 32 KB
    __shared__ float4 p_lds[16][32];               // 8 KB
    const float4* hs4 = (const float4*)(hs + ((size_t)b * NN + nc * 128) * DD);
#pragma unroll
    for (int k = 0; k < 8; ++k)
        ((float4*)hs_lds)[t + k * 256] = hs4[t + k * 256];
#pragma unroll
    for (int k = 0; k < 2; ++k) {
        int i4 = t + k * 256;                      // 512 float4
        int ml = i4 >> 5, n4 = i4 & 31;
        p_lds[ml][n4] = ((const float4*)(pt +
            ((size_t)(b * MM + mt * 16 + ml)) * NN + nc * 128))[n4];
    }
    __syncthreads();
    int d = t & 63, g = t >> 6;
    float acc[4] = {0.f, 0.f, 0.f, 0.f};
    for (int n4 = 0; n4 < 32; ++n4) {
        float h0 = hs_lds[n4 * 4 + 0][d], h1 = hs_lds[n4 * 4 + 1][d];
        float h2 = hs_lds[n4 * 4 + 2][d], h3 = hs_lds[n4 * 4 + 3][d];
#pragma unroll
        for (int j = 0; j < 4; ++j) {
            float4 p = p_lds[g * 4 + j][n4];
            acc[j] += p.x * h0 + p.y * h1 + p.z * h2 + p.w * h3;
        }
    }
#pragma unroll
    for (int j = 0; j < 4; ++j) {
        int mg = mt * 16 + g * 4 + j;
        pbuf[(((size_t)b * 16 + nc) * MM + mg) * DD + d] = acc[j];
    }
}

// ---------------------------------------------------------------------------
// agg2: out[bm,d] = sigmoid(W_edge[d]*ssfe[bm] + sum_nc pbuf[...])
// ---------------------------------------------------------------------------
__global__ __launch_bounds__(256) void agg2_kernel(
        const float* __restrict__ pbuf, const float* __restrict__ ssfe,
        const float* __restrict__ W_edge, float* __restrict__ out) {
    int gid = blockIdx.x * 256 + threadIdx.x;      // 32768
    int d = gid & 63, bm = gid >> 6;
    int b = bm >> 7, m = bm & 127;
    float s = 0.f;
#pragma unroll
    for (int nc = 0; nc < 16; ++nc)
        s += pbuf[(((size_t)b * 16 + nc) * MM + m) * DD + d];
    float v = W_edge[d] * ssfe[bm] + s;
    out[(size_t)bm * DD + d] = 1.f / (1.f + expf(-v));
}

extern "C" void kernel_launch(void* const* d_in, const int* in_sizes, int n_in,
                              void* d_out, int out_size, void* d_ws, size_t ws_size,
                              hipStream_t stream) {
    const float* feat_src  = (const float*)d_in[0];
    const float* feat_dst  = (const float*)d_in[1];
    const float* feat_edge = (const float*)d_in[2];
    const int*   adj       = (const int*)d_in[3];
    const float* W_src     = (const float*)d_in[4];
    const float* W_dst     = (const float*)d_in[5];
    const float* W_edge    = (const float*)d_in[6];
    const float* attn_l    = (const float*)d_in[7];
    const float* attn_r    = (const float*)d_in[8];
    const float* attn_e    = (const float*)d_in[9];
    float* out = (float*)d_out;

    float* ws   = (float*)d_ws;
    float* hs   = ws;                        // 524288
    float* el   = hs + (size_t)BB * NN * DD; // 8192
    float* er   = el + BB * NN;              // 512
    float* st_s = er + BB * MM;              // 1048576
    float* st_f = st_s + (size_t)BB * MM * NN;
    float* pt   = st_f + (size_t)BB * MM * NN;
    float* ssfe = pt + (size_t)BB * MM * NN; // 512
    float* pbuf = ssfe + BB * MM;            // 524288

    proj_kernel<<<(BB * NN) / 16, 256, 0, stream>>>(feat_src, W_src, attn_l, hs, el);
    er_kernel<<<2, 256, 0, stream>>>(feat_dst, W_dst, attn_r, er);
    ts_kernel<<<dim3(NN / 32, BB), 256, 0, stream>>>(feat_edge, adj, el, er,
                                                     W_edge, attn_e, st_s, st_f);
    soft_kernel<<<BB * MM, 256, 0, stream>>>(st_s, st_f, pt, ssfe);
    agg1_kernel<<<dim3(16, 8, BB), 256, 0, stream>>>(pt, hs, pbuf);
    agg2_kernel<<<128, 256, 0, stream>>>(pbuf, ssfe, W_edge, out);
}